// Round 1
// baseline (1275.420 us; speedup 1.0000x reference)
//
#include <hip/hip_runtime.h>
#include <math.h>

#define H 128
#define TN 32

// ---------------- CSR build ----------------

__global__ __launch_bounds__(256) void zero_ints(int* __restrict__ p, int n) {
    int i = blockIdx.x * 256 + threadIdx.x;
    if (i < n) p[i] = 0;
}

__global__ __launch_bounds__(256) void hist_deg(const int* __restrict__ ei, int E,
                                                int* __restrict__ deg) {
    int e = blockIdx.x * 256 + threadIdx.x;
    if (e < E) atomicAdd(&deg[ei[E + e]], 1);  // dst row of edge_index
}

__global__ __launch_bounds__(256) void block_sums(const int* __restrict__ deg,
                                                  int* __restrict__ bsum, int N) {
    __shared__ int part[4];
    int tid = threadIdx.x;
    int i = blockIdx.x * 256 + tid;
    int v = (i < N) ? deg[i] : 0;
#pragma unroll
    for (int off = 32; off > 0; off >>= 1) v += __shfl_down(v, off, 64);
    if ((tid & 63) == 0) part[tid >> 6] = v;
    __syncthreads();
    if (tid == 0) bsum[blockIdx.x] = part[0] + part[1] + part[2] + part[3];
}

__global__ __launch_bounds__(64) void scan_bsum(const int* __restrict__ bsum,
                                                int* __restrict__ bbase, int NB,
                                                int* __restrict__ totalOut) {
    int lane = threadIdx.x;
    int base = 0;
    for (int s0 = 0; s0 < NB; s0 += 64) {
        int i = s0 + lane;
        int v = (i < NB) ? bsum[i] : 0;
        int incl = v;
#pragma unroll
        for (int off = 1; off < 64; off <<= 1) {
            int t = __shfl_up(incl, off, 64);
            if (lane >= off) incl += t;
        }
        if (i < NB) bbase[i] = base + incl - v;
        base += __shfl(incl, 63, 64);
    }
    if (lane == 0) *totalOut = base;  // offsets[N] = E
}

__global__ __launch_bounds__(256) void scan_within(const int* __restrict__ deg,
                                                   const int* __restrict__ bbase,
                                                   int* __restrict__ offsets, int N) {
    __shared__ int buf[256];
    int tid = threadIdx.x;
    int i = blockIdx.x * 256 + tid;
    int v = (i < N) ? deg[i] : 0;
    int incl = v;
    buf[tid] = v;
    __syncthreads();
#pragma unroll
    for (int off = 1; off < 256; off <<= 1) {
        int t = (tid >= off) ? buf[tid - off] : 0;
        __syncthreads();
        incl += t;
        buf[tid] = incl;
        __syncthreads();
    }
    if (i < N) offsets[i] = bbase[blockIdx.x] + incl - v;  // exclusive scan
}

__global__ __launch_bounds__(256) void fill_adj(const int* __restrict__ ei, int E,
                                                const int* __restrict__ offsets,
                                                int* __restrict__ cursor,
                                                int* __restrict__ adj) {
    int e = blockIdx.x * 256 + threadIdx.x;
    if (e < E) {
        int s = ei[e];
        int d = ei[E + e];
        int pos = atomicAdd(&cursor[d], 1);
        adj[offsets[d] + pos] = s;
    }
}

// ---------------- query normalization ----------------

__global__ __launch_bounds__(128) void prep_query(const float* __restrict__ query,
                                                  float* __restrict__ qn) {
    int g = blockIdx.x;
    int f = threadIdx.x;
    float v = query[g * H + f];
    float ss = v * v;
#pragma unroll
    for (int off = 32; off > 0; off >>= 1) ss += __shfl_xor(ss, off, 64);
    __shared__ float part[2];
    if ((f & 63) == 0) part[f >> 6] = ss;
    __syncthreads();
    float tot = part[0] + part[1];
    qn[g * H + f] = v / fmaxf(sqrtf(tot), 1e-12f);
}

// ---------------- fused gather-max + dual GEMM + relu (one SAGE layer) ----------------
// Block: 256 threads, computes TN=32 nodes x 128 outs.
// thread: j = tid&127 (out col), s = tid>>7 (node half); 16 fp32 acc per thread.

__global__ __launch_bounds__(256) void layer_kernel(
    const float* __restrict__ xin, const float* __restrict__ Wl,
    const float* __restrict__ bl, const float* __restrict__ Wr,
    const int* __restrict__ offsets, const int* __restrict__ adj,
    float* __restrict__ xout, int N) {
    __shared__ __align__(16) float a_tiles[2][TN][H];  // [0]=m (seg-max), [1]=x
    __shared__ float w_t[32][H + 1];                   // k-chunk of W, transposed, padded

    int tid = threadIdx.x;
    int j = tid & 127;
    int s = tid >> 7;
    int n0 = blockIdx.x * TN;

    // Phase 1: stage x-tile and compute segment-max tile directly into LDS.
    // 128 threads (2 waves) per node; adj[e]/offsets are wave-uniform.
    for (int r = 0; r < TN; r += 2) {
        int row = r + s;
        int n = n0 + row;
        float v = 0.f, best = 0.f;
        if (n < N) {
            v = xin[n * H + j];
            int e0 = offsets[n], e1 = offsets[n + 1];
            if (e1 > e0) {
                best = -INFINITY;
                for (int e = e0; e < e1; ++e) {
                    best = fmaxf(best, xin[adj[e] * H + j]);
                }
            }
            // deg==0 -> best stays 0 (reference: isfinite fixup)
        }
        a_tiles[1][row][j] = v;
        a_tiles[0][row][j] = best;
    }

    float acc[16];
    float bias = bl[j];
#pragma unroll
    for (int t = 0; t < 16; ++t) acc[t] = bias;

#pragma unroll
    for (int pass = 0; pass < 2; ++pass) {
        const float* W = (pass == 0) ? Wl : Wr;
        const float* A = &a_tiles[pass][0][0];
        for (int kc = 0; kc < 4; ++kc) {
            __syncthreads();
            // stage w_t[kk][jj] = W[jj][kc*32+kk]  (coalesced global, conflict-free LDS)
            int kk = tid & 31;
            int jr0 = tid >> 5;
#pragma unroll
            for (int i = 0; i < 16; ++i) {
                int jj = jr0 + i * 8;
                w_t[kk][jj] = W[jj * H + kc * 32 + kk];
            }
            __syncthreads();
#pragma unroll
            for (int k4 = 0; k4 < 8; ++k4) {
                float w0 = w_t[k4 * 4 + 0][j];
                float w1 = w_t[k4 * 4 + 1][j];
                float w2 = w_t[k4 * 4 + 2][j];
                float w3 = w_t[k4 * 4 + 3][j];
#pragma unroll
                for (int t = 0; t < 16; ++t) {
                    const float4 a = *(const float4*)(A + (s * 16 + t) * H + kc * 32 + k4 * 4);
                    acc[t] = fmaf(a.x, w0, acc[t]);
                    acc[t] = fmaf(a.y, w1, acc[t]);
                    acc[t] = fmaf(a.z, w2, acc[t]);
                    acc[t] = fmaf(a.w, w3, acc[t]);
                }
            }
        }
    }

#pragma unroll
    for (int t = 0; t < 16; ++t) {
        int n = n0 + s * 16 + t;
        if (n < N) xout[n * H + j] = fmaxf(acc[t], 0.f);
    }
}

// ---------------- final linear + cosine score ----------------

__global__ __launch_bounds__(256) void final_kernel(
    const float* __restrict__ xin, const float* __restrict__ Wlin,
    const float* __restrict__ blin, const float* __restrict__ qn,
    const int* __restrict__ bv, float* __restrict__ out, int N) {
    __shared__ __align__(16) float x_tile[TN][H];
    __shared__ float w_t[32][H + 1];

    int tid = threadIdx.x;
    int j = tid & 127;
    int s = tid >> 7;
    int n0 = blockIdx.x * TN;

    for (int r = 0; r < TN; r += 2) {
        int row = r + s;
        int n = n0 + row;
        x_tile[row][j] = (n < N) ? xin[n * H + j] : 0.f;
    }

    float acc[16];
    float bias = blin[j];
#pragma unroll
    for (int t = 0; t < 16; ++t) acc[t] = bias;

    for (int kc = 0; kc < 4; ++kc) {
        __syncthreads();
        int kk = tid & 31;
        int jr0 = tid >> 5;
#pragma unroll
        for (int i = 0; i < 16; ++i) {
            int jj = jr0 + i * 8;
            w_t[kk][jj] = Wlin[jj * H + kc * 32 + kk];
        }
        __syncthreads();
#pragma unroll
        for (int k4 = 0; k4 < 8; ++k4) {
            float w0 = w_t[k4 * 4 + 0][j];
            float w1 = w_t[k4 * 4 + 1][j];
            float w2 = w_t[k4 * 4 + 2][j];
            float w3 = w_t[k4 * 4 + 3][j];
#pragma unroll
            for (int t = 0; t < 16; ++t) {
                const float4 a = *(const float4*)(&x_tile[s * 16 + t][kc * 32 + k4 * 4]);
                acc[t] = fmaf(a.x, w0, acc[t]);
                acc[t] = fmaf(a.y, w1, acc[t]);
                acc[t] = fmaf(a.z, w2, acc[t]);
                acc[t] = fmaf(a.w, w3, acc[t]);
            }
        }
    }

    // write y back over x_tile, then per-node cosine reduction (8 lanes/node)
    __syncthreads();
#pragma unroll
    for (int t = 0; t < 16; ++t) x_tile[s * 16 + t][j] = acc[t];
    __syncthreads();

    int node = tid >> 3;
    int lane8 = tid & 7;
    int n = n0 + node;
    float ss = 0.f, sd = 0.f;
    if (n < N) {
        const float* q = qn + bv[n] * H;
        for (int f = lane8; f < H; f += 8) {
            float y = x_tile[node][f];
            ss += y * y;
            sd += y * q[f];
        }
    }
#pragma unroll
    for (int off = 1; off < 8; off <<= 1) {
        ss += __shfl_xor(ss, off, 64);
        sd += __shfl_xor(sd, off, 64);
    }
    if (lane8 == 0 && n < N) {
        out[n] = sd / fmaxf(sqrtf(ss), 1e-12f);
    }
}

// ---------------- launch ----------------

extern "C" void kernel_launch(void* const* d_in, const int* in_sizes, int n_in,
                              void* d_out, int out_size, void* d_ws, size_t ws_size,
                              hipStream_t stream) {
    const float* x = (const float*)d_in[0];
    const float* query = (const float*)d_in[1];
    const float* Wl = (const float*)d_in[2];
    const float* bl = (const float*)d_in[3];
    const float* Wr = (const float*)d_in[4];
    const float* Wlin = (const float*)d_in[5];
    const float* blin = (const float*)d_in[6];
    const int* ei = (const int*)d_in[7];
    const int* bv = (const int*)d_in[8];
    float* out = (float*)d_out;

    const int N = in_sizes[0] / H;
    const int E = in_sizes[7] / 2;
    const int G = in_sizes[1] / H;
    const int NB = (N + 255) / 256;

    char* p = (char*)d_ws;
    auto alloc = [&](size_t bytes) {
        char* r = p;
        p += (bytes + 255) & ~(size_t)255;
        return r;
    };
    int* deg = (int*)alloc((size_t)2 * N * sizeof(int));  // deg then cursor
    int* cursor = deg + N;
    int* offsets = (int*)alloc((size_t)(N + 1) * sizeof(int));
    int* bsum = (int*)alloc((size_t)NB * sizeof(int));
    int* bbase = (int*)alloc((size_t)NB * sizeof(int));
    int* adj = (int*)alloc((size_t)E * sizeof(int));
    float* qn = (float*)alloc((size_t)G * H * sizeof(float));
    float* xb0 = (float*)alloc((size_t)N * H * sizeof(float));
    float* xb1 = (float*)alloc((size_t)N * H * sizeof(float));

    zero_ints<<<(2 * N + 255) / 256, 256, 0, stream>>>(deg, 2 * N);
    hist_deg<<<(E + 255) / 256, 256, 0, stream>>>(ei, E, deg);
    block_sums<<<NB, 256, 0, stream>>>(deg, bsum, N);
    scan_bsum<<<1, 64, 0, stream>>>(bsum, bbase, NB, offsets + N);
    scan_within<<<NB, 256, 0, stream>>>(deg, bbase, offsets, N);
    fill_adj<<<(E + 255) / 256, 256, 0, stream>>>(ei, E, offsets, cursor, adj);
    prep_query<<<G, 128, 0, stream>>>(query, qn);

    int NGB = (N + TN - 1) / TN;
    layer_kernel<<<NGB, 256, 0, stream>>>(x, Wl + 0 * H * H, bl + 0 * H, Wr + 0 * H * H,
                                          offsets, adj, xb0, N);
    layer_kernel<<<NGB, 256, 0, stream>>>(xb0, Wl + 1 * H * H, bl + 1 * H, Wr + 1 * H * H,
                                          offsets, adj, xb1, N);
    layer_kernel<<<NGB, 256, 0, stream>>>(xb1, Wl + 2 * H * H, bl + 2 * H, Wr + 2 * H * H,
                                          offsets, adj, xb0, N);
    final_kernel<<<NGB, 256, 0, stream>>>(xb0, Wlin, blin, qn, bv, out, N);
}

// Round 2
// 612.993 us; speedup vs baseline: 2.0806x; 2.0806x over previous
//
#include <hip/hip_runtime.h>
#include <math.h>

#define H 128

// ---------------- CSR build ----------------

__global__ __launch_bounds__(256) void zero_ints(int* __restrict__ p, int n) {
    int i = blockIdx.x * 256 + threadIdx.x;
    if (i < n) p[i] = 0;
}

__global__ __launch_bounds__(256) void hist_deg(const int* __restrict__ ei, int E,
                                                int* __restrict__ deg) {
    int e = blockIdx.x * 256 + threadIdx.x;
    if (e < E) atomicAdd(&deg[ei[E + e]], 1);  // dst row of edge_index
}

__global__ __launch_bounds__(256) void block_sums(const int* __restrict__ deg,
                                                  int* __restrict__ bsum, int N) {
    __shared__ int part[4];
    int tid = threadIdx.x;
    int i = blockIdx.x * 256 + tid;
    int v = (i < N) ? deg[i] : 0;
#pragma unroll
    for (int off = 32; off > 0; off >>= 1) v += __shfl_down(v, off, 64);
    if ((tid & 63) == 0) part[tid >> 6] = v;
    __syncthreads();
    if (tid == 0) bsum[blockIdx.x] = part[0] + part[1] + part[2] + part[3];
}

__global__ __launch_bounds__(64) void scan_bsum(const int* __restrict__ bsum,
                                                int* __restrict__ bbase, int NB,
                                                int* __restrict__ totalOut) {
    int lane = threadIdx.x;
    int base = 0;
    for (int s0 = 0; s0 < NB; s0 += 64) {
        int i = s0 + lane;
        int v = (i < NB) ? bsum[i] : 0;
        int incl = v;
#pragma unroll
        for (int off = 1; off < 64; off <<= 1) {
            int t = __shfl_up(incl, off, 64);
            if (lane >= off) incl += t;
        }
        if (i < NB) bbase[i] = base + incl - v;
        base += __shfl(incl, 63, 64);
    }
    if (lane == 0) *totalOut = base;  // offsets[N] = E
}

__global__ __launch_bounds__(256) void scan_within(const int* __restrict__ deg,
                                                   const int* __restrict__ bbase,
                                                   int* __restrict__ offsets, int N) {
    __shared__ int buf[256];
    int tid = threadIdx.x;
    int i = blockIdx.x * 256 + tid;
    int v = (i < N) ? deg[i] : 0;
    int incl = v;
    buf[tid] = v;
    __syncthreads();
#pragma unroll
    for (int off = 1; off < 256; off <<= 1) {
        int t = (tid >= off) ? buf[tid - off] : 0;
        __syncthreads();
        incl += t;
        buf[tid] = incl;
        __syncthreads();
    }
    if (i < N) offsets[i] = bbase[blockIdx.x] + incl - v;  // exclusive scan
}

__global__ __launch_bounds__(256) void fill_adj(const int* __restrict__ ei, int E,
                                                const int* __restrict__ offsets,
                                                int* __restrict__ cursor,
                                                int* __restrict__ adj) {
    int e = blockIdx.x * 256 + threadIdx.x;
    if (e < E) {
        int s = ei[e];
        int d = ei[E + e];
        int pos = atomicAdd(&cursor[d], 1);
        adj[offsets[d] + pos] = s;
    }
}

// ---------------- query normalization ----------------

__global__ __launch_bounds__(128) void prep_query(const float* __restrict__ query,
                                                  float* __restrict__ qn) {
    int g = blockIdx.x;
    int f = threadIdx.x;
    float v = query[g * H + f];
    float ss = v * v;
#pragma unroll
    for (int off = 32; off > 0; off >>= 1) ss += __shfl_xor(ss, off, 64);
    __shared__ float part[2];
    if ((f & 63) == 0) part[f >> 6] = ss;
    __syncthreads();
    float tot = part[0] + part[1];
    qn[g * H + f] = v / fmaxf(sqrtf(tot), 1e-12f);
}

// ---------------- gather-max (segment max over CSR) ----------------
// 32 lanes per node (float4 each), 8 nodes per 256-thread block.
// 4-way unrolled degree loop -> 4 independent row-loads in flight.

__device__ __forceinline__ float4 f4max(float4 a, float4 b) {
    float4 r;
    r.x = fmaxf(a.x, b.x);
    r.y = fmaxf(a.y, b.y);
    r.z = fmaxf(a.z, b.z);
    r.w = fmaxf(a.w, b.w);
    return r;
}

__global__ __launch_bounds__(256) void gather_max(
    const float4* __restrict__ xin4, const int* __restrict__ offsets,
    const int* __restrict__ adj, float4* __restrict__ m4, int N) {
    int tid = threadIdx.x;
    int f4 = tid & 31;
    int node = blockIdx.x * 8 + (tid >> 5);
    if (node >= N) return;
    int e0 = offsets[node], e1 = offsets[node + 1];
    float4 b = make_float4(0.f, 0.f, 0.f, 0.f);
    if (e1 > e0) {
        float4 b0 = make_float4(-INFINITY, -INFINITY, -INFINITY, -INFINITY);
        float4 b1 = b0, b2 = b0, b3 = b0;
        int e = e0;
        for (; e + 4 <= e1; e += 4) {
            int a0 = adj[e + 0];
            int a1 = adj[e + 1];
            int a2 = adj[e + 2];
            int a3 = adj[e + 3];
            float4 v0 = xin4[(size_t)a0 * 32 + f4];
            float4 v1 = xin4[(size_t)a1 * 32 + f4];
            float4 v2 = xin4[(size_t)a2 * 32 + f4];
            float4 v3 = xin4[(size_t)a3 * 32 + f4];
            b0 = f4max(b0, v0);
            b1 = f4max(b1, v1);
            b2 = f4max(b2, v2);
            b3 = f4max(b3, v3);
        }
        for (; e < e1; ++e) {
            b0 = f4max(b0, xin4[(size_t)adj[e] * 32 + f4]);
        }
        b = f4max(f4max(b0, b1), f4max(b2, b3));
        // deg>0 guarantees at least one finite value folded into b0;
        // any untouched accumulators are -inf and lose the max.
    }
    m4[(size_t)node * 32 + f4] = b;
}

// ---------------- dual GEMM + bias + relu: relu(m@Wl^T + bl + x@Wr^T) ----------------
// Block 256, tile 64 rows x 128 cols; thread = 8 rows x 4 cols (32 fp32 acc).
// Single A-tile buffer, two passes (A=m with Wl, then A=x with Wr).

#define TN2 64

__global__ __launch_bounds__(256) void gemm_relu(
    const float* __restrict__ A0, const float* __restrict__ A1,
    const float* __restrict__ Wl, const float* __restrict__ bl,
    const float* __restrict__ Wr, float* __restrict__ xout, int N) {
    __shared__ __align__(16) float a_t[TN2][H];   // 32 KB
    __shared__ __align__(16) float w_t[32][132];  // 16.9 KB, padded stride (16B-aligned)

    int tid = threadIdx.x;
    int c = tid & 31;   // col quad: cols 4c..4c+3
    int rg = tid >> 5;  // row group: rows rg*8..rg*8+7
    int n0 = blockIdx.x * TN2;

    float4 acc[8];
    float4 bias = *(const float4*)&bl[c * 4];
#pragma unroll
    for (int r = 0; r < 8; ++r) acc[r] = bias;

    for (int pass = 0; pass < 2; ++pass) {
        const float* A = pass ? A1 : A0;
        const float* W = pass ? Wr : Wl;

        __syncthreads();  // previous pass done reading a_t
        {
            int j = tid & 127;
            int r0 = tid >> 7;
#pragma unroll
            for (int rr = 0; rr < 32; ++rr) {
                int r = rr * 2 + r0;
                int n = n0 + r;
                a_t[r][j] = (n < N) ? A[(size_t)n * H + j] : 0.f;
            }
        }

        for (int kc = 0; kc < 4; ++kc) {
            __syncthreads();  // protect w_t (and a_t on first iter)
            {
                int kk = tid & 31;
                int j0 = tid >> 5;
#pragma unroll
                for (int i = 0; i < 16; ++i) {
                    int j = j0 + i * 8;
                    w_t[kk][j] = W[(size_t)j * H + kc * 32 + kk];
                }
            }
            __syncthreads();
#pragma unroll
            for (int q = 0; q < 8; ++q) {
                float4 a[8];
#pragma unroll
                for (int r = 0; r < 8; ++r)
                    a[r] = *(const float4*)&a_t[rg * 8 + r][kc * 32 + q * 4];
#pragma unroll
                for (int kk = 0; kk < 4; ++kk) {
                    float4 w = *(const float4*)&w_t[q * 4 + kk][c * 4];
#pragma unroll
                    for (int r = 0; r < 8; ++r) {
                        float av = (kk == 0) ? a[r].x
                                 : (kk == 1) ? a[r].y
                                 : (kk == 2) ? a[r].z
                                             : a[r].w;
                        acc[r].x = fmaf(av, w.x, acc[r].x);
                        acc[r].y = fmaf(av, w.y, acc[r].y);
                        acc[r].z = fmaf(av, w.z, acc[r].z);
                        acc[r].w = fmaf(av, w.w, acc[r].w);
                    }
                }
            }
        }
    }

#pragma unroll
    for (int r = 0; r < 8; ++r) {
        int n = n0 + rg * 8 + r;
        if (n < N) {
            float4 o;
            o.x = fmaxf(acc[r].x, 0.f);
            o.y = fmaxf(acc[r].y, 0.f);
            o.z = fmaxf(acc[r].z, 0.f);
            o.w = fmaxf(acc[r].w, 0.f);
            *(float4*)&xout[(size_t)n * H + c * 4] = o;
        }
    }
}

// ---------------- final linear + cosine score ----------------

#define TN 32

__global__ __launch_bounds__(256) void final_kernel(
    const float* __restrict__ xin, const float* __restrict__ Wlin,
    const float* __restrict__ blin, const float* __restrict__ qn,
    const int* __restrict__ bv, float* __restrict__ out, int N) {
    __shared__ __align__(16) float x_tile[TN][H];
    __shared__ float w_t[32][H + 1];

    int tid = threadIdx.x;
    int j = tid & 127;
    int s = tid >> 7;
    int n0 = blockIdx.x * TN;

    for (int r = 0; r < TN; r += 2) {
        int row = r + s;
        int n = n0 + row;
        x_tile[row][j] = (n < N) ? xin[n * H + j] : 0.f;
    }

    float acc[16];
    float bias = blin[j];
#pragma unroll
    for (int t = 0; t < 16; ++t) acc[t] = bias;

    for (int kc = 0; kc < 4; ++kc) {
        __syncthreads();
        int kk = tid & 31;
        int jr0 = tid >> 5;
#pragma unroll
        for (int i = 0; i < 16; ++i) {
            int jj = jr0 + i * 8;
            w_t[kk][jj] = Wlin[jj * H + kc * 32 + kk];
        }
        __syncthreads();
#pragma unroll
        for (int k4 = 0; k4 < 8; ++k4) {
            float w0 = w_t[k4 * 4 + 0][j];
            float w1 = w_t[k4 * 4 + 1][j];
            float w2 = w_t[k4 * 4 + 2][j];
            float w3 = w_t[k4 * 4 + 3][j];
#pragma unroll
            for (int t = 0; t < 16; ++t) {
                const float4 a = *(const float4*)(&x_tile[s * 16 + t][kc * 32 + k4 * 4]);
                acc[t] = fmaf(a.x, w0, acc[t]);
                acc[t] = fmaf(a.y, w1, acc[t]);
                acc[t] = fmaf(a.z, w2, acc[t]);
                acc[t] = fmaf(a.w, w3, acc[t]);
            }
        }
    }

    __syncthreads();
#pragma unroll
    for (int t = 0; t < 16; ++t) x_tile[s * 16 + t][j] = acc[t];
    __syncthreads();

    int node = tid >> 3;
    int lane8 = tid & 7;
    int n = n0 + node;
    float ss = 0.f, sd = 0.f;
    if (n < N) {
        const float* q = qn + bv[n] * H;
        for (int f = lane8; f < H; f += 8) {
            float y = x_tile[node][f];
            ss += y * y;
            sd += y * q[f];
        }
    }
#pragma unroll
    for (int off = 1; off < 8; off <<= 1) {
        ss += __shfl_xor(ss, off, 64);
        sd += __shfl_xor(sd, off, 64);
    }
    if (lane8 == 0 && n < N) {
        out[n] = sd / fmaxf(sqrtf(ss), 1e-12f);
    }
}

// ---------------- launch ----------------

extern "C" void kernel_launch(void* const* d_in, const int* in_sizes, int n_in,
                              void* d_out, int out_size, void* d_ws, size_t ws_size,
                              hipStream_t stream) {
    const float* x = (const float*)d_in[0];
    const float* query = (const float*)d_in[1];
    const float* Wl = (const float*)d_in[2];
    const float* bl = (const float*)d_in[3];
    const float* Wr = (const float*)d_in[4];
    const float* Wlin = (const float*)d_in[5];
    const float* blin = (const float*)d_in[6];
    const int* ei = (const int*)d_in[7];
    const int* bv = (const int*)d_in[8];
    float* out = (float*)d_out;

    const int N = in_sizes[0] / H;
    const int E = in_sizes[7] / 2;
    const int G = in_sizes[1] / H;
    const int NB = (N + 255) / 256;

    char* p = (char*)d_ws;
    auto alloc = [&](size_t bytes) {
        char* r = p;
        p += (bytes + 255) & ~(size_t)255;
        return r;
    };
    int* deg = (int*)alloc((size_t)2 * N * sizeof(int));  // deg then cursor
    int* cursor = deg + N;
    int* offsets = (int*)alloc((size_t)(N + 1) * sizeof(int));
    int* bsum = (int*)alloc((size_t)NB * sizeof(int));
    int* bbase = (int*)alloc((size_t)NB * sizeof(int));
    int* adj = (int*)alloc((size_t)E * sizeof(int));
    float* qn = (float*)alloc((size_t)G * H * sizeof(float));
    float* mbuf = (float*)alloc((size_t)N * H * sizeof(float));
    float* xb0 = (float*)alloc((size_t)N * H * sizeof(float));
    float* xb1 = (float*)alloc((size_t)N * H * sizeof(float));

    zero_ints<<<(2 * N + 255) / 256, 256, 0, stream>>>(deg, 2 * N);
    hist_deg<<<(E + 255) / 256, 256, 0, stream>>>(ei, E, deg);
    block_sums<<<NB, 256, 0, stream>>>(deg, bsum, N);
    scan_bsum<<<1, 64, 0, stream>>>(bsum, bbase, NB, offsets + N);
    scan_within<<<NB, 256, 0, stream>>>(deg, bbase, offsets, N);
    fill_adj<<<(E + 255) / 256, 256, 0, stream>>>(ei, E, offsets, cursor, adj);
    prep_query<<<G, 128, 0, stream>>>(query, qn);

    const int NGg = (N + 7) / 8;          // gather blocks
    const int NGm = (N + TN2 - 1) / TN2;  // gemm blocks
    const int NGf = (N + TN - 1) / TN;    // final blocks

    gather_max<<<NGg, 256, 0, stream>>>((const float4*)x, offsets, adj,
                                        (float4*)mbuf, N);
    gemm_relu<<<NGm, 256, 0, stream>>>(mbuf, x, Wl + 0 * H * H, bl + 0 * H,
                                       Wr + 0 * H * H, xb0, N);
    gather_max<<<NGg, 256, 0, stream>>>((const float4*)xb0, offsets, adj,
                                        (float4*)mbuf, N);
    gemm_relu<<<NGm, 256, 0, stream>>>(mbuf, xb0, Wl + 1 * H * H, bl + 1 * H,
                                       Wr + 1 * H * H, xb1, N);
    gather_max<<<NGg, 256, 0, stream>>>((const float4*)xb1, offsets, adj,
                                        (float4*)mbuf, N);
    gemm_relu<<<NGm, 256, 0, stream>>>(mbuf, xb1, Wl + 2 * H * H, bl + 2 * H,
                                       Wr + 2 * H * H, xb0, N);
    final_kernel<<<NGf, 256, 0, stream>>>(xb0, Wlin, blin, qn, bv, out, N);
}

// Round 3
// 520.888 us; speedup vs baseline: 2.4485x; 1.1768x over previous
//
#include <hip/hip_runtime.h>
#include <math.h>

#define H 128

// ---------------- CSR build ----------------

__global__ __launch_bounds__(256) void zero_ints(int* __restrict__ p, int n) {
    int i = blockIdx.x * 256 + threadIdx.x;
    if (i < n) p[i] = 0;
}

__global__ __launch_bounds__(256) void hist_deg(const int* __restrict__ ei, int E,
                                                int* __restrict__ deg) {
    int e = blockIdx.x * 256 + threadIdx.x;
    if (e < E) atomicAdd(&deg[ei[E + e]], 1);  // dst row of edge_index
}

__global__ __launch_bounds__(256) void block_sums(const int* __restrict__ deg,
                                                  int* __restrict__ bsum, int N) {
    __shared__ int part[4];
    int tid = threadIdx.x;
    int i = blockIdx.x * 256 + tid;
    int v = (i < N) ? deg[i] : 0;
#pragma unroll
    for (int off = 32; off > 0; off >>= 1) v += __shfl_down(v, off, 64);
    if ((tid & 63) == 0) part[tid >> 6] = v;
    __syncthreads();
    if (tid == 0) bsum[blockIdx.x] = part[0] + part[1] + part[2] + part[3];
}

__global__ __launch_bounds__(64) void scan_bsum(const int* __restrict__ bsum,
                                                int* __restrict__ bbase, int NB,
                                                int* __restrict__ totalOut) {
    int lane = threadIdx.x;
    int base = 0;
    for (int s0 = 0; s0 < NB; s0 += 64) {
        int i = s0 + lane;
        int v = (i < NB) ? bsum[i] : 0;
        int incl = v;
#pragma unroll
        for (int off = 1; off < 64; off <<= 1) {
            int t = __shfl_up(incl, off, 64);
            if (lane >= off) incl += t;
        }
        if (i < NB) bbase[i] = base + incl - v;
        base += __shfl(incl, 63, 64);
    }
    if (lane == 0) *totalOut = base;  // offsets[N] = E
}

__global__ __launch_bounds__(256) void scan_within(const int* __restrict__ deg,
                                                   const int* __restrict__ bbase,
                                                   int* __restrict__ offsets, int N) {
    __shared__ int buf[256];
    int tid = threadIdx.x;
    int i = blockIdx.x * 256 + tid;
    int v = (i < N) ? deg[i] : 0;
    int incl = v;
    buf[tid] = v;
    __syncthreads();
#pragma unroll
    for (int off = 1; off < 256; off <<= 1) {
        int t = (tid >= off) ? buf[tid - off] : 0;
        __syncthreads();
        incl += t;
        buf[tid] = incl;
        __syncthreads();
    }
    if (i < N) offsets[i] = bbase[blockIdx.x] + incl - v;  // exclusive scan
}

__global__ __launch_bounds__(256) void fill_adj(const int* __restrict__ ei, int E,
                                                const int* __restrict__ offsets,
                                                int* __restrict__ cursor,
                                                int* __restrict__ adj) {
    int e = blockIdx.x * 256 + threadIdx.x;
    if (e < E) {
        int s = ei[e];
        int d = ei[E + e];
        int pos = atomicAdd(&cursor[d], 1);
        adj[offsets[d] + pos] = s;
    }
}

// ---------------- query normalization ----------------

__global__ __launch_bounds__(128) void prep_query(const float* __restrict__ query,
                                                  float* __restrict__ qn) {
    int g = blockIdx.x;
    int f = threadIdx.x;
    float v = query[g * H + f];
    float ss = v * v;
#pragma unroll
    for (int off = 32; off > 0; off >>= 1) ss += __shfl_xor(ss, off, 64);
    __shared__ float part[2];
    if ((f & 63) == 0) part[f >> 6] = ss;
    __syncthreads();
    float tot = part[0] + part[1];
    qn[g * H + f] = v / fmaxf(sqrtf(tot), 1e-12f);
}

// ---------------- gather-max (segment max over CSR) ----------------
// 32 lanes per node (float4 each), 8 nodes per 256-thread block.
// 8 independent accumulators -> 8 row-loads in flight per thread.

__device__ __forceinline__ float4 f4max(float4 a, float4 b) {
    float4 r;
    r.x = fmaxf(a.x, b.x);
    r.y = fmaxf(a.y, b.y);
    r.z = fmaxf(a.z, b.z);
    r.w = fmaxf(a.w, b.w);
    return r;
}

__global__ __launch_bounds__(256) void gather_max(
    const float4* __restrict__ xin4, const int* __restrict__ offsets,
    const int* __restrict__ adj, float4* __restrict__ m4, int N) {
    int tid = threadIdx.x;
    int f4 = tid & 31;
    int node = blockIdx.x * 8 + (tid >> 5);
    if (node >= N) return;
    int e0 = offsets[node], e1 = offsets[node + 1];
    float4 b = make_float4(0.f, 0.f, 0.f, 0.f);
    if (e1 > e0) {
        const float4 ninf = make_float4(-INFINITY, -INFINITY, -INFINITY, -INFINITY);
        float4 acc[8];
#pragma unroll
        for (int u = 0; u < 8; ++u) acc[u] = ninf;
        int e = e0;
        for (; e + 8 <= e1; e += 8) {
            int a[8];
#pragma unroll
            for (int u = 0; u < 8; ++u) a[u] = adj[e + u];
            float4 v[8];
#pragma unroll
            for (int u = 0; u < 8; ++u) v[u] = xin4[(size_t)a[u] * 32 + f4];
#pragma unroll
            for (int u = 0; u < 8; ++u) acc[u] = f4max(acc[u], v[u]);
        }
        for (; e + 4 <= e1; e += 4) {
            int a[4];
#pragma unroll
            for (int u = 0; u < 4; ++u) a[u] = adj[e + u];
#pragma unroll
            for (int u = 0; u < 4; ++u)
                acc[u] = f4max(acc[u], xin4[(size_t)a[u] * 32 + f4]);
        }
        for (; e < e1; ++e) {
            acc[0] = f4max(acc[0], xin4[(size_t)adj[e] * 32 + f4]);
        }
#pragma unroll
        for (int u = 4; u < 8; ++u) acc[u - 4] = f4max(acc[u - 4], acc[u]);
        b = f4max(f4max(acc[0], acc[1]), f4max(acc[2], acc[3]));
        // deg>0 guarantees at least one finite value folded in; untouched
        // accumulators stay -inf and lose the max.
    }
    m4[(size_t)node * 32 + f4] = b;
}

// ---------------- dual GEMM + bias + relu: relu(m@Wl^T + bl + x@Wr^T) ----------------
// Block 256, tile 64 rows x 128 cols; thread = 8 rows x 4 cols (32 fp32 acc).
// Single A-tile buffer, two passes (A=m with Wl, then A=x with Wr).

#define TN2 64

__global__ __launch_bounds__(256) void gemm_relu(
    const float* __restrict__ A0, const float* __restrict__ A1,
    const float* __restrict__ Wl, const float* __restrict__ bl,
    const float* __restrict__ Wr, float* __restrict__ xout, int N) {
    __shared__ __align__(16) float a_t[TN2][H];   // 32 KB
    __shared__ __align__(16) float w_t[32][132];  // 16.9 KB, padded stride (16B-aligned)

    int tid = threadIdx.x;
    int c = tid & 31;   // col quad: cols 4c..4c+3
    int rg = tid >> 5;  // row group: rows rg*8..rg*8+7
    int n0 = blockIdx.x * TN2;

    float4 acc[8];
    float4 bias = *(const float4*)&bl[c * 4];
#pragma unroll
    for (int r = 0; r < 8; ++r) acc[r] = bias;

    for (int pass = 0; pass < 2; ++pass) {
        const float* A = pass ? A1 : A0;
        const float* W = pass ? Wr : Wl;

        __syncthreads();  // previous pass done reading a_t
        {
            const float4* A4 = (const float4*)A;
            float4* a4 = (float4*)&a_t[0][0];
#pragma unroll
            for (int i = 0; i < 8; ++i) {
                int idx = tid + i * 256;  // [0, 2048)
                int r = idx >> 5;
                int n = n0 + r;
                float4 v = make_float4(0.f, 0.f, 0.f, 0.f);
                if (n < N) v = A4[(size_t)n * 32 + (idx & 31)];
                a4[idx] = v;
            }
        }

        for (int kc = 0; kc < 4; ++kc) {
            __syncthreads();  // protect w_t (and a_t on first iter)
            {
                int kk = tid & 31;
                int j0 = tid >> 5;
#pragma unroll
                for (int i = 0; i < 16; ++i) {
                    int j = j0 + i * 8;
                    w_t[kk][j] = W[(size_t)j * H + kc * 32 + kk];
                }
            }
            __syncthreads();
#pragma unroll
            for (int q = 0; q < 8; ++q) {
                float4 a[8];
#pragma unroll
                for (int r = 0; r < 8; ++r)
                    a[r] = *(const float4*)&a_t[rg * 8 + r][kc * 32 + q * 4];
#pragma unroll
                for (int kk = 0; kk < 4; ++kk) {
                    float4 w = *(const float4*)&w_t[q * 4 + kk][c * 4];
#pragma unroll
                    for (int r = 0; r < 8; ++r) {
                        float av = (kk == 0) ? a[r].x
                                 : (kk == 1) ? a[r].y
                                 : (kk == 2) ? a[r].z
                                             : a[r].w;
                        acc[r].x = fmaf(av, w.x, acc[r].x);
                        acc[r].y = fmaf(av, w.y, acc[r].y);
                        acc[r].z = fmaf(av, w.z, acc[r].z);
                        acc[r].w = fmaf(av, w.w, acc[r].w);
                    }
                }
            }
        }
    }

#pragma unroll
    for (int r = 0; r < 8; ++r) {
        int n = n0 + rg * 8 + r;
        if (n < N) {
            float4 o;
            o.x = fmaxf(acc[r].x, 0.f);
            o.y = fmaxf(acc[r].y, 0.f);
            o.z = fmaxf(acc[r].z, 0.f);
            o.w = fmaxf(acc[r].w, 0.f);
            *(float4*)&xout[(size_t)n * H + c * 4] = o;
        }
    }
}

// ---------------- final linear + cosine score (fused, gemm-style) ----------------
// Same tiling as gemm_relu; epilogue reduces y.y and y.q across the 32 lanes
// (c=0..31) that own one row, via width-32 shuffles (no LDS round-trip).

__global__ __launch_bounds__(256) void final_kernel(
    const float* __restrict__ xin, const float* __restrict__ Wlin,
    const float* __restrict__ blin, const float* __restrict__ qn,
    const int* __restrict__ bv, float* __restrict__ out, int N) {
    __shared__ __align__(16) float a_t[TN2][H];   // 32 KB
    __shared__ __align__(16) float w_t[32][132];  // 16.9 KB

    int tid = threadIdx.x;
    int c = tid & 31;
    int rg = tid >> 5;
    int n0 = blockIdx.x * TN2;

    {
        const float4* A4 = (const float4*)xin;
        float4* a4 = (float4*)&a_t[0][0];
#pragma unroll
        for (int i = 0; i < 8; ++i) {
            int idx = tid + i * 256;
            int r = idx >> 5;
            int n = n0 + r;
            float4 v = make_float4(0.f, 0.f, 0.f, 0.f);
            if (n < N) v = A4[(size_t)n * 32 + (idx & 31)];
            a4[idx] = v;
        }
    }

    float4 acc[8];
    float4 bias = *(const float4*)&blin[c * 4];
#pragma unroll
    for (int r = 0; r < 8; ++r) acc[r] = bias;

    for (int kc = 0; kc < 4; ++kc) {
        __syncthreads();  // protect w_t (and a_t on first iter)
        {
            int kk = tid & 31;
            int j0 = tid >> 5;
#pragma unroll
            for (int i = 0; i < 16; ++i) {
                int j = j0 + i * 8;
                w_t[kk][j] = Wlin[(size_t)j * H + kc * 32 + kk];
            }
        }
        __syncthreads();
#pragma unroll
        for (int q = 0; q < 8; ++q) {
            float4 a[8];
#pragma unroll
            for (int r = 0; r < 8; ++r)
                a[r] = *(const float4*)&a_t[rg * 8 + r][kc * 32 + q * 4];
#pragma unroll
            for (int kk = 0; kk < 4; ++kk) {
                float4 w = *(const float4*)&w_t[q * 4 + kk][c * 4];
#pragma unroll
                for (int r = 0; r < 8; ++r) {
                    float av = (kk == 0) ? a[r].x
                             : (kk == 1) ? a[r].y
                             : (kk == 2) ? a[r].z
                                         : a[r].w;
                    acc[r].x = fmaf(av, w.x, acc[r].x);
                    acc[r].y = fmaf(av, w.y, acc[r].y);
                    acc[r].z = fmaf(av, w.z, acc[r].z);
                    acc[r].w = fmaf(av, w.w, acc[r].w);
                }
            }
        }
    }

    // cosine epilogue: row r is owned by the 32 lanes sharing rg (contiguous
    // half-wave); width-32 xor shuffles stay inside the half.
#pragma unroll
    for (int r = 0; r < 8; ++r) {
        int n = n0 + rg * 8 + r;
        float4 y = acc[r];
        int g = (n < N) ? bv[n] : 0;
        float4 q = *(const float4*)&qn[(size_t)g * H + c * 4];
        float ss = y.x * y.x + y.y * y.y + y.z * y.z + y.w * y.w;
        float sd = y.x * q.x + y.y * q.y + y.z * q.z + y.w * q.w;
#pragma unroll
        for (int off = 1; off < 32; off <<= 1) {
            ss += __shfl_xor(ss, off, 64);
            sd += __shfl_xor(sd, off, 64);
        }
        if (c == 0 && n < N) out[n] = sd / fmaxf(sqrtf(ss), 1e-12f);
    }
}

// ---------------- launch ----------------

extern "C" void kernel_launch(void* const* d_in, const int* in_sizes, int n_in,
                              void* d_out, int out_size, void* d_ws, size_t ws_size,
                              hipStream_t stream) {
    const float* x = (const float*)d_in[0];
    const float* query = (const float*)d_in[1];
    const float* Wl = (const float*)d_in[2];
    const float* bl = (const float*)d_in[3];
    const float* Wr = (const float*)d_in[4];
    const float* Wlin = (const float*)d_in[5];
    const float* blin = (const float*)d_in[6];
    const int* ei = (const int*)d_in[7];
    const int* bv = (const int*)d_in[8];
    float* out = (float*)d_out;

    const int N = in_sizes[0] / H;
    const int E = in_sizes[7] / 2;
    const int G = in_sizes[1] / H;
    const int NB = (N + 255) / 256;

    char* p = (char*)d_ws;
    auto alloc = [&](size_t bytes) {
        char* r = p;
        p += (bytes + 255) & ~(size_t)255;
        return r;
    };
    int* deg = (int*)alloc((size_t)2 * N * sizeof(int));  // deg then cursor
    int* cursor = deg + N;
    int* offsets = (int*)alloc((size_t)(N + 1) * sizeof(int));
    int* bsum = (int*)alloc((size_t)NB * sizeof(int));
    int* bbase = (int*)alloc((size_t)NB * sizeof(int));
    int* adj = (int*)alloc((size_t)E * sizeof(int));
    float* qn = (float*)alloc((size_t)G * H * sizeof(float));
    float* mbuf = (float*)alloc((size_t)N * H * sizeof(float));
    float* xb0 = (float*)alloc((size_t)N * H * sizeof(float));
    float* xb1 = (float*)alloc((size_t)N * H * sizeof(float));

    zero_ints<<<(2 * N + 255) / 256, 256, 0, stream>>>(deg, 2 * N);
    hist_deg<<<(E + 255) / 256, 256, 0, stream>>>(ei, E, deg);
    block_sums<<<NB, 256, 0, stream>>>(deg, bsum, N);
    scan_bsum<<<1, 64, 0, stream>>>(bsum, bbase, NB, offsets + N);
    scan_within<<<NB, 256, 0, stream>>>(deg, bbase, offsets, N);
    fill_adj<<<(E + 255) / 256, 256, 0, stream>>>(ei, E, offsets, cursor, adj);
    prep_query<<<G, 128, 0, stream>>>(query, qn);

    const int NGg = (N + 7) / 8;          // gather blocks
    const int NGm = (N + TN2 - 1) / TN2;  // gemm/final blocks

    gather_max<<<NGg, 256, 0, stream>>>((const float4*)x, offsets, adj,
                                        (float4*)mbuf, N);
    gemm_relu<<<NGm, 256, 0, stream>>>(mbuf, x, Wl + 0 * H * H, bl + 0 * H,
                                       Wr + 0 * H * H, xb0, N);
    gather_max<<<NGg, 256, 0, stream>>>((const float4*)xb0, offsets, adj,
                                        (float4*)mbuf, N);
    gemm_relu<<<NGm, 256, 0, stream>>>(mbuf, xb0, Wl + 1 * H * H, bl + 1 * H,
                                       Wr + 1 * H * H, xb1, N);
    gather_max<<<NGg, 256, 0, stream>>>((const float4*)xb1, offsets, adj,
                                        (float4*)mbuf, N);
    gemm_relu<<<NGm, 256, 0, stream>>>(mbuf, xb1, Wl + 2 * H * H, bl + 2 * H,
                                       Wr + 2 * H * H, xb0, N);
    final_kernel<<<NGm, 256, 0, stream>>>(xb0, Wlin, blin, qn, bv, out, N);
}

// Round 4
// 397.960 us; speedup vs baseline: 3.2049x; 1.3089x over previous
//
#include <hip/hip_runtime.h>
#include <math.h>

#define H 128

typedef _Float16 half8 __attribute__((ext_vector_type(8)));
typedef float f32x16 __attribute__((ext_vector_type(16)));

// ---------------- CSR build ----------------

__global__ __launch_bounds__(256) void zero_ints(int* __restrict__ p, int n) {
    int i = blockIdx.x * 256 + threadIdx.x;
    if (i < n) p[i] = 0;
}

__global__ __launch_bounds__(256) void hist_deg(const int* __restrict__ ei, int E,
                                                int* __restrict__ deg) {
    int e = blockIdx.x * 256 + threadIdx.x;
    if (e < E) atomicAdd(&deg[ei[E + e]], 1);  // dst row of edge_index
}

__global__ __launch_bounds__(256) void block_sums(const int* __restrict__ deg,
                                                  int* __restrict__ bsum, int N) {
    __shared__ int part[4];
    int tid = threadIdx.x;
    int i = blockIdx.x * 256 + tid;
    int v = (i < N) ? deg[i] : 0;
#pragma unroll
    for (int off = 32; off > 0; off >>= 1) v += __shfl_down(v, off, 64);
    if ((tid & 63) == 0) part[tid >> 6] = v;
    __syncthreads();
    if (tid == 0) bsum[blockIdx.x] = part[0] + part[1] + part[2] + part[3];
}

__global__ __launch_bounds__(64) void scan_bsum(const int* __restrict__ bsum,
                                                int* __restrict__ bbase, int NB,
                                                int* __restrict__ totalOut) {
    int lane = threadIdx.x;
    int base = 0;
    for (int s0 = 0; s0 < NB; s0 += 64) {
        int i = s0 + lane;
        int v = (i < NB) ? bsum[i] : 0;
        int incl = v;
#pragma unroll
        for (int off = 1; off < 64; off <<= 1) {
            int t = __shfl_up(incl, off, 64);
            if (lane >= off) incl += t;
        }
        if (i < NB) bbase[i] = base + incl - v;
        base += __shfl(incl, 63, 64);
    }
    if (lane == 0) *totalOut = base;  // offsets[N] = E
}

__global__ __launch_bounds__(256) void scan_within(const int* __restrict__ deg,
                                                   const int* __restrict__ bbase,
                                                   int* __restrict__ offsets, int N) {
    __shared__ int buf[256];
    int tid = threadIdx.x;
    int i = blockIdx.x * 256 + tid;
    int v = (i < N) ? deg[i] : 0;
    int incl = v;
    buf[tid] = v;
    __syncthreads();
#pragma unroll
    for (int off = 1; off < 256; off <<= 1) {
        int t = (tid >= off) ? buf[tid - off] : 0;
        __syncthreads();
        incl += t;
        buf[tid] = incl;
        __syncthreads();
    }
    if (i < N) offsets[i] = bbase[blockIdx.x] + incl - v;  // exclusive scan
}

__global__ __launch_bounds__(256) void fill_adj(const int* __restrict__ ei, int E,
                                                const int* __restrict__ offsets,
                                                int* __restrict__ cursor,
                                                int* __restrict__ adj) {
    int e = blockIdx.x * 256 + threadIdx.x;
    if (e < E) {
        int s = ei[e];
        int d = ei[E + e];
        int pos = atomicAdd(&cursor[d], 1);
        adj[offsets[d] + pos] = s;
    }
}

// ---------------- query normalization ----------------

__global__ __launch_bounds__(128) void prep_query(const float* __restrict__ query,
                                                  float* __restrict__ qn) {
    int g = blockIdx.x;
    int f = threadIdx.x;
    float v = query[g * H + f];
    float ss = v * v;
#pragma unroll
    for (int off = 32; off > 0; off >>= 1) ss += __shfl_xor(ss, off, 64);
    __shared__ float part[2];
    if ((f & 63) == 0) part[f >> 6] = ss;
    __syncthreads();
    float tot = part[0] + part[1];
    qn[g * H + f] = v / fmaxf(sqrtf(tot), 1e-12f);
}

// ---------------- weight split + fragment-image packing ----------------
// Splits each fp32 weight into (hi, lo) fp16 and packs LDS-ready images:
// image(mat, hl, chunk)[n][pos] where pos = g ^ (n&7) (XOR swizzle), granule
// g = 8 contiguous k. One image = 128 rows x 8 granules x 8 halves = 16 KB.
// mat order: Wl0,Wr0,Wl1,Wr1,Wl2,Wr2,Wlin.  Total 7*2*2*8192 halves = 448 KB.

__global__ __launch_bounds__(256) void prep_wsplit(const float* __restrict__ Wl,
                                                   const float* __restrict__ Wr,
                                                   const float* __restrict__ Wlin,
                                                   _Float16* __restrict__ img) {
    int gidx = blockIdx.x * 256 + threadIdx.x;  // granule id
    if (gidx >= 7 * 128 * 16) return;
    int mat = gidx / (128 * 16);
    int rem = gidx - mat * (128 * 16);
    int n = rem >> 4;
    int g16 = rem & 15;  // granule within K=128
    const float* src = (mat == 6) ? Wlin
                     : ((mat & 1) ? Wr + (mat >> 1) * H * H : Wl + (mat >> 1) * H * H);
    const float* p = src + n * H + g16 * 8;
    half8 h, l;
#pragma unroll
    for (int j = 0; j < 8; ++j) {
        float v = p[j];
        _Float16 hh = (_Float16)v;
        h[j] = hh;
        l[j] = (_Float16)(v - (float)hh);
    }
    int chunk = g16 >> 3, g = g16 & 7;
    int pos = g ^ (n & 7);
    size_t b_hi = (((size_t)mat * 2 + 0) * 2 + chunk) * 8192 + n * 64 + pos * 8;
    size_t b_lo = (((size_t)mat * 2 + 1) * 2 + chunk) * 8192 + n * 64 + pos * 8;
    *(half8*)(img + b_hi) = h;
    *(half8*)(img + b_lo) = l;
}

// ---------------- gather-max (segment max over CSR) ----------------
// 32 lanes per node (float4 each), 8 nodes per 256-thread block.
// Clamp trick: out-of-range lanes re-read e1-1 (duplicates are max-neutral),
// so all 8 unrolled loads always issue -> no serial remainder.

__device__ __forceinline__ float4 f4max(float4 a, float4 b) {
    float4 r;
    r.x = fmaxf(a.x, b.x);
    r.y = fmaxf(a.y, b.y);
    r.z = fmaxf(a.z, b.z);
    r.w = fmaxf(a.w, b.w);
    return r;
}

__global__ __launch_bounds__(256) void gather_max(
    const float4* __restrict__ xin4, const int* __restrict__ offsets,
    const int* __restrict__ adj, float4* __restrict__ m4, int N) {
    int tid = threadIdx.x;
    int f4 = tid & 31;
    int node = blockIdx.x * 8 + (tid >> 5);
    if (node >= N) return;
    int e0 = offsets[node], e1 = offsets[node + 1];
    float4 b = make_float4(0.f, 0.f, 0.f, 0.f);
    if (e1 > e0) {
        const float4 ninf = make_float4(-INFINITY, -INFINITY, -INFINITY, -INFINITY);
        float4 acc[8];
#pragma unroll
        for (int u = 0; u < 8; ++u) acc[u] = ninf;
        for (int base = e0; base < e1; base += 8) {
            int a[8];
#pragma unroll
            for (int u = 0; u < 8; ++u) {
                int ee = base + u;
                a[u] = adj[ee < e1 ? ee : e1 - 1];
            }
            float4 v[8];
#pragma unroll
            for (int u = 0; u < 8; ++u) v[u] = xin4[(size_t)a[u] * 32 + f4];
#pragma unroll
            for (int u = 0; u < 8; ++u) acc[u] = f4max(acc[u], v[u]);
        }
#pragma unroll
        for (int u = 4; u < 8; ++u) acc[u - 4] = f4max(acc[u - 4], acc[u]);
        b = f4max(f4max(acc[0], acc[1]), f4max(acc[2], acc[3]));
    }
    m4[(size_t)node * 32 + f4] = b;
}

// ---------------- MFMA split-fp16 dual GEMM + bias + relu ----------------
// C = relu(A0 @ Wl^T + bl + A1 @ Wr^T), fp32-accurate via fp16 hi/lo x3 MFMA.
// 1 wave per block (wave-synchronous, zero barriers). Wave tile 64x128:
// m_t=2 x n_t=4 32x32 tiles, acc = 8 x f32x16 = 128 VGPR.
// A-fragments straight from global (row-major == A-operand layout), split
// in-register. B chunks copied from prepacked images into LDS.

__device__ __forceinline__ void split8(const float* f, half8& h, half8& l) {
#pragma unroll
    for (int j = 0; j < 8; ++j) {
        float v = f[j];
        _Float16 hh = (_Float16)v;
        h[j] = hh;
        l[j] = (_Float16)(v - (float)hh);
    }
}

__global__ __launch_bounds__(64, 2) void gemm_mfma(
    const float* __restrict__ A0, const float* __restrict__ A1,
    const _Float16* __restrict__ wimg,  // layer base: [pass][hl][chunk] 8192 halves
    const float* __restrict__ bl, float* __restrict__ xout, int N) {
    __shared__ half8 sB[2][1024];  // [hl][n*8 + pos], 16 KB each

    int lane = threadIdx.x;
    int l31 = lane & 31;
    int lhi = lane >> 5;
    int n0 = blockIdx.x * 64;

    f32x16 acc[2][4];
#pragma unroll
    for (int nt = 0; nt < 4; ++nt) {
        float bv = bl[nt * 32 + l31];
#pragma unroll
        for (int m = 0; m < 2; ++m)
#pragma unroll
            for (int r = 0; r < 16; ++r) acc[m][nt][r] = bv;
    }

    for (int pass = 0; pass < 2; ++pass) {
        const float* A = pass ? A1 : A0;
        const float4* A4 = (const float4*)A;
        for (int chunk = 0; chunk < 2; ++chunk) {
            // stage B chunk (hi+lo): straight copy, 16 half8 per lane per matrix
            {
                const half8* s0 =
                    (const half8*)(wimg + ((size_t)pass * 4 + 0 * 2 + chunk) * 8192);
                const half8* s1 =
                    (const half8*)(wimg + ((size_t)pass * 4 + 1 * 2 + chunk) * 8192);
#pragma unroll
                for (int i = 0; i < 16; ++i) {
                    sB[0][lane + i * 64] = s0[lane + i * 64];
                    sB[1][lane + i * 64] = s1[lane + i * 64];
                }
            }
            // wave-synchronous: compiler inserts the lgkmcnt wait on first read
#pragma unroll
            for (int kstep = 0; kstep < 4; ++kstep) {
                half8 ah[2], al[2];
#pragma unroll
                for (int m = 0; m < 2; ++m) {
                    int row = n0 + m * 32 + l31;
                    row = row < N ? row : N - 1;
                    const float4* ap =
                        A4 + (size_t)row * 32 + chunk * 16 + kstep * 4 + lhi * 2;
                    float tmp[8];
                    *(float4*)tmp = ap[0];
                    *(float4*)(tmp + 4) = ap[1];
                    split8(tmp, ah[m], al[m]);
                }
                half8 bh[4], blo[4];
#pragma unroll
                for (int nt = 0; nt < 4; ++nt) {
                    int n = nt * 32 + l31;
                    int pos = (kstep * 2 + lhi) ^ (n & 7);
                    bh[nt] = sB[0][n * 8 + pos];
                    blo[nt] = sB[1][n * 8 + pos];
                }
#pragma unroll
                for (int m = 0; m < 2; ++m)
#pragma unroll
                    for (int nt = 0; nt < 4; ++nt) {
                        acc[m][nt] = __builtin_amdgcn_mfma_f32_32x32x16_f16(
                            ah[m], bh[nt], acc[m][nt], 0, 0, 0);
                        acc[m][nt] = __builtin_amdgcn_mfma_f32_32x32x16_f16(
                            al[m], bh[nt], acc[m][nt], 0, 0, 0);
                        acc[m][nt] = __builtin_amdgcn_mfma_f32_32x32x16_f16(
                            ah[m], blo[nt], acc[m][nt], 0, 0, 0);
                    }
            }
        }
    }

    // epilogue: relu + store. C/D: col = lane&31, row = (r&3)+8*(r>>2)+4*lhi
#pragma unroll
    for (int m = 0; m < 2; ++m)
#pragma unroll
        for (int r = 0; r < 16; ++r) {
            int row = n0 + m * 32 + (r & 3) + 8 * (r >> 2) + 4 * lhi;
            if (row < N) {
#pragma unroll
                for (int nt = 0; nt < 4; ++nt) {
                    xout[(size_t)row * H + nt * 32 + l31] = fmaxf(acc[m][nt][r], 0.f);
                }
            }
        }
}

// ---------------- MFMA final linear + cosine score ----------------

__global__ __launch_bounds__(64, 2) void final_mfma(
    const float* __restrict__ xin, const _Float16* __restrict__ wimg,  // Wlin base
    const float* __restrict__ blin, const float* __restrict__ qn,
    const int* __restrict__ bv, float* __restrict__ out, int N) {
    __shared__ half8 sB[2][1024];

    int lane = threadIdx.x;
    int l31 = lane & 31;
    int lhi = lane >> 5;
    int n0 = blockIdx.x * 64;

    f32x16 acc[2][4];
#pragma unroll
    for (int nt = 0; nt < 4; ++nt) {
        float bvv = blin[nt * 32 + l31];
#pragma unroll
        for (int m = 0; m < 2; ++m)
#pragma unroll
            for (int r = 0; r < 16; ++r) acc[m][nt][r] = bvv;
    }

    const float4* A4 = (const float4*)xin;
    for (int chunk = 0; chunk < 2; ++chunk) {
        {
            const half8* s0 = (const half8*)(wimg + ((size_t)0 * 2 + chunk) * 8192);
            const half8* s1 = (const half8*)(wimg + ((size_t)1 * 2 + chunk) * 8192);
#pragma unroll
            for (int i = 0; i < 16; ++i) {
                sB[0][lane + i * 64] = s0[lane + i * 64];
                sB[1][lane + i * 64] = s1[lane + i * 64];
            }
        }
#pragma unroll
        for (int kstep = 0; kstep < 4; ++kstep) {
            half8 ah[2], al[2];
#pragma unroll
            for (int m = 0; m < 2; ++m) {
                int row = n0 + m * 32 + l31;
                row = row < N ? row : N - 1;
                const float4* ap = A4 + (size_t)row * 32 + chunk * 16 + kstep * 4 + lhi * 2;
                float tmp[8];
                *(float4*)tmp = ap[0];
                *(float4*)(tmp + 4) = ap[1];
                split8(tmp, ah[m], al[m]);
            }
            half8 bh[4], blo[4];
#pragma unroll
            for (int nt = 0; nt < 4; ++nt) {
                int n = nt * 32 + l31;
                int pos = (kstep * 2 + lhi) ^ (n & 7);
                bh[nt] = sB[0][n * 8 + pos];
                blo[nt] = sB[1][n * 8 + pos];
            }
#pragma unroll
            for (int m = 0; m < 2; ++m)
#pragma unroll
                for (int nt = 0; nt < 4; ++nt) {
                    acc[m][nt] = __builtin_amdgcn_mfma_f32_32x32x16_f16(
                        ah[m], bh[nt], acc[m][nt], 0, 0, 0);
                    acc[m][nt] = __builtin_amdgcn_mfma_f32_32x32x16_f16(
                        al[m], bh[nt], acc[m][nt], 0, 0, 0);
                    acc[m][nt] = __builtin_amdgcn_mfma_f32_32x32x16_f16(
                        ah[m], blo[nt], acc[m][nt], 0, 0, 0);
                }
        }
    }

    // cosine epilogue: per output row, reduce over the 32 lanes (l31) that
    // hold its 128 cols (4 nt x 32). xor masks <=16 never cross the lhi halves.
#pragma unroll
    for (int m = 0; m < 2; ++m)
#pragma unroll
        for (int r = 0; r < 16; ++r) {
            int row = n0 + m * 32 + (r & 3) + 8 * (r >> 2) + 4 * lhi;
            int rowc = row < N ? row : N - 1;
            int g = bv[rowc];
            float ss = 0.f, sd = 0.f;
#pragma unroll
            for (int nt = 0; nt < 4; ++nt) {
                float y = acc[m][nt][r];
                float q = qn[(size_t)g * H + nt * 32 + l31];
                ss = fmaf(y, y, ss);
                sd = fmaf(y, q, sd);
            }
#pragma unroll
            for (int off = 1; off <= 16; off <<= 1) {
                ss += __shfl_xor(ss, off, 64);
                sd += __shfl_xor(sd, off, 64);
            }
            if (l31 == 0 && row < N) out[row] = sd / fmaxf(sqrtf(ss), 1e-12f);
        }
}

// ---------------- launch ----------------

extern "C" void kernel_launch(void* const* d_in, const int* in_sizes, int n_in,
                              void* d_out, int out_size, void* d_ws, size_t ws_size,
                              hipStream_t stream) {
    const float* x = (const float*)d_in[0];
    const float* query = (const float*)d_in[1];
    const float* Wl = (const float*)d_in[2];
    const float* bl = (const float*)d_in[3];
    const float* Wr = (const float*)d_in[4];
    const float* Wlin = (const float*)d_in[5];
    const float* blin = (const float*)d_in[6];
    const int* ei = (const int*)d_in[7];
    const int* bv = (const int*)d_in[8];
    float* out = (float*)d_out;

    const int N = in_sizes[0] / H;
    const int E = in_sizes[7] / 2;
    const int G = in_sizes[1] / H;
    const int NB = (N + 255) / 256;

    char* p = (char*)d_ws;
    auto alloc = [&](size_t bytes) {
        char* r = p;
        p += (bytes + 255) & ~(size_t)255;
        return r;
    };
    int* deg = (int*)alloc((size_t)2 * N * sizeof(int));  // deg then cursor
    int* cursor = deg + N;
    int* offsets = (int*)alloc((size_t)(N + 1) * sizeof(int));
    int* bsum = (int*)alloc((size_t)NB * sizeof(int));
    int* bbase = (int*)alloc((size_t)NB * sizeof(int));
    int* adj = (int*)alloc((size_t)E * sizeof(int));
    float* qn = (float*)alloc((size_t)G * H * sizeof(float));
    _Float16* wimg = (_Float16*)alloc((size_t)7 * 32768 * sizeof(_Float16));
    float* mbuf = (float*)alloc((size_t)N * H * sizeof(float));
    float* xb0 = (float*)alloc((size_t)N * H * sizeof(float));
    float* xb1 = (float*)alloc((size_t)N * H * sizeof(float));

    zero_ints<<<(2 * N + 255) / 256, 256, 0, stream>>>(deg, 2 * N);
    hist_deg<<<(E + 255) / 256, 256, 0, stream>>>(ei, E, deg);
    block_sums<<<NB, 256, 0, stream>>>(deg, bsum, N);
    scan_bsum<<<1, 64, 0, stream>>>(bsum, bbase, NB, offsets + N);
    scan_within<<<NB, 256, 0, stream>>>(deg, bbase, offsets, N);
    fill_adj<<<(E + 255) / 256, 256, 0, stream>>>(ei, E, offsets, cursor, adj);
    prep_query<<<G, 128, 0, stream>>>(query, qn);
    prep_wsplit<<<(7 * 128 * 16 + 255) / 256, 256, 0, stream>>>(Wl, Wr, Wlin, wimg);

    const int NGg = (N + 7) / 8;    // gather blocks
    const int NGm = (N + 63) / 64;  // mfma gemm blocks (1 wave each)

    gather_max<<<NGg, 256, 0, stream>>>((const float4*)x, offsets, adj,
                                        (float4*)mbuf, N);
    gemm_mfma<<<NGm, 64, 0, stream>>>(mbuf, x, wimg + 0 * 65536, bl + 0 * H, xb0, N);
    gather_max<<<NGg, 256, 0, stream>>>((const float4*)xb0, offsets, adj,
                                        (float4*)mbuf, N);
    gemm_mfma<<<NGm, 64, 0, stream>>>(mbuf, xb0, wimg + 1 * 65536, bl + 1 * H, xb1, N);
    gather_max<<<NGg, 256, 0, stream>>>((const float4*)xb1, offsets, adj,
                                        (float4*)mbuf, N);
    gemm_mfma<<<NGm, 64, 0, stream>>>(mbuf, xb1, wimg + 2 * 65536, bl + 2 * H, xb0, N);
    final_mfma<<<NGm, 64, 0, stream>>>(xb0, wimg + 6 * 32768, blin, qn, bv, out, N);
}